// Round 4
// baseline (443.586 us; speedup 1.0000x reference)
//
#include <hip/hip_runtime.h>
#include <stdint.h>

typedef short short8 __attribute__((ext_vector_type(8)));
typedef float f32x4 __attribute__((ext_vector_type(4)));

__device__ __forceinline__ float bf2f(unsigned short u) {
    union { unsigned int i; float f; } v; v.i = ((unsigned int)u) << 16; return v.f;
}
__device__ __forceinline__ unsigned short f2bf(float f) {
    union { float f; unsigned int i; } v; v.f = f;
    unsigned int u = v.i;
    unsigned int r = (u + 0x7fffu + ((u >> 16) & 1u)) >> 16;
    return (unsigned short)r;
}

// ---------------- kernel 0: weight transpose (f32 -> bf16 hi, + lo for f/g) -
// wTh[320][256]; wTl[64][256] (lo part only for f,g columns)
__global__ void k_wtrans(const float* __restrict__ Wf,
                         const float* __restrict__ Wg,
                         const float* __restrict__ Wh,
                         unsigned short* __restrict__ wTh,
                         unsigned short* __restrict__ wTl) {
    int col = blockIdx.x;   // 0..319
    int k = threadIdx.x;    // 0..255
    float v;
    if (col < 32) v = Wf[k * 32 + col];
    else if (col < 64) v = Wg[k * 32 + (col - 32)];
    else v = Wh[k * 256 + (col - 64)];
    unsigned short h = f2bf(v);
    wTh[col * 256 + k] = h;
    if (col < 64) wTl[col * 256 + k] = f2bf(v - bf2f(h));
}

// ---------------- kernel 1: fused projection GEMM --------------------------
// One block per 64-row tile (grid 256). Stages x (hi+lo) once per K-phase,
// loops over 5 column blocks: cb 0..3 = h cols (1-term), cb 4 = f,g (3-term
// hi/lo split). h written transposed via LDS (128B row stores). f,g stored
// as bf16 hi/lo pairs.
__global__ __launch_bounds__(256) void k_proj(
    const float* __restrict__ x,
    const unsigned short* __restrict__ wTh,
    const unsigned short* __restrict__ wTl,
    const float* __restrict__ bfb,
    const float* __restrict__ bgb,
    const float* __restrict__ bhb,
    unsigned short* __restrict__ fKh,
    unsigned short* __restrict__ fKl,
    unsigned short* __restrict__ gQh,
    unsigned short* __restrict__ gQl,
    unsigned short* __restrict__ hT) {
    __shared__ short sm[4 * 64 * 136];   // XH, XL, WH, WL [64][128->136]
    const int XH = 0, XL = 64 * 136, WH = 2 * 64 * 136, WL = 3 * 64 * 136;
    int tid = threadIdx.x;
    int wave = tid >> 6, lane = tid & 63, lq = lane & 15, quad = lane >> 4;
    int rt = blockIdx.x;   // row tile 0..255
    const float* xbase = x + (size_t)rt * 64 * 256;

    f32x4 zero4 = {0.f, 0.f, 0.f, 0.f};
    f32x4 acc[5][4];
#pragma unroll
    for (int cb = 0; cb < 5; ++cb)
#pragma unroll
        for (int ct = 0; ct < 4; ++ct) acc[cb][ct] = zero4;

    for (int ph = 0; ph < 2; ++ph) {
        int k0 = ph * 128;
        __syncthreads();
        // stage x tile (hi+lo)
#pragma unroll
        for (int u = 0; u < 4; ++u) {
            int q = u * 256 + tid;
            int row = q >> 4, kc = q & 15;
            const float* src = &xbase[row * 256 + k0 + kc * 8];
            f32x4 a0 = *(const f32x4*)src;
            f32x4 a1 = *(const f32x4*)(src + 4);
            short8 sh, sl;
#pragma unroll
            for (int j = 0; j < 4; ++j) {
                unsigned short h0 = f2bf(a0[j]);
                sh[j] = (short)h0; sl[j] = (short)f2bf(a0[j] - bf2f(h0));
                unsigned short h1 = f2bf(a1[j]);
                sh[4 + j] = (short)h1; sl[4 + j] = (short)f2bf(a1[j] - bf2f(h1));
            }
            *(short8*)&sm[XH + row * 136 + kc * 8] = sh;
            *(short8*)&sm[XL + row * 136 + kc * 8] = sl;
        }
        for (int cb = 0; cb < 5; ++cb) {
            __syncthreads();
            // stage W tile: rows = output cols (h: 64+cb*64.., fg: 0..63)
            int cstart = (cb < 4) ? (64 + cb * 64) : 0;
#pragma unroll
            for (int u = 0; u < 4; ++u) {
                int q = u * 256 + tid;
                int row = q >> 4, kc = q & 15;
                *(short8*)&sm[WH + row * 136 + kc * 8] =
                    *(const short8*)&wTh[(cstart + row) * 256 + k0 + kc * 8];
            }
            if (cb == 4) {
#pragma unroll
                for (int u = 0; u < 4; ++u) {
                    int q = u * 256 + tid;
                    int row = q >> 4, kc = q & 15;
                    *(short8*)&sm[WL + row * 136 + kc * 8] =
                        *(const short8*)&wTl[row * 256 + k0 + kc * 8];
                }
            }
            __syncthreads();
#pragma unroll
            for (int ks = 0; ks < 4; ++ks) {
                short8 ah = *(const short8*)&sm[XH + (wave * 16 + lq) * 136 + ks * 32 + quad * 8];
                short8 al = *(const short8*)&sm[XL + (wave * 16 + lq) * 136 + ks * 32 + quad * 8];
#pragma unroll
                for (int ct = 0; ct < 4; ++ct) {
                    short8 bh = *(const short8*)&sm[WH + (lq + 16 * ct) * 136 + ks * 32 + quad * 8];
                    acc[cb][ct] = __builtin_amdgcn_mfma_f32_16x16x32_bf16(ah, bh, acc[cb][ct], 0, 0, 0);
                    if (cb == 4) {
                        short8 bl = *(const short8*)&sm[WL + (lq + 16 * ct) * 136 + ks * 32 + quad * 8];
                        acc[cb][ct] = __builtin_amdgcn_mfma_f32_16x16x32_bf16(al, bh, acc[cb][ct], 0, 0, 0);
                        acc[cb][ct] = __builtin_amdgcn_mfma_f32_16x16x32_bf16(ah, bl, acc[cb][ct], 0, 0, 0);
                    }
                }
            }
        }
    }

    int grow0 = rt * 64;
    int bidx = grow0 >> 12, n0 = grow0 & 4095;

    // ---- h epilogue: transpose via LDS, store 16B row chunks ----
    for (int cb = 0; cb < 4; ++cb) {
        __syncthreads();
        int rowl = wave * 16 + quad * 4;
#pragma unroll
        for (int ct = 0; ct < 4; ++ct) {
            int cl = lq + 16 * ct;
            float bias = bhb[cb * 64 + cl];
#pragma unroll
            for (int r = 0; r < 4; ++r)
                sm[XH + cl * 72 + rowl + r] = (short)f2bf(acc[cb][ct][r] + bias);
        }
        __syncthreads();
#pragma unroll
        for (int i = 0; i < 2; ++i) {
            int idx = i * 256 + tid;       // 0..511
            int c = idx >> 3, ch = idx & 7;
            *(short8*)&hT[((size_t)(bidx * 256 + cb * 64 + c)) * 4096 + n0 + ch * 8] =
                *(const short8*)&sm[XH + c * 72 + ch * 8];
        }
    }

    // ---- f,g epilogue: hi/lo pairs ----
    {
        int rowl = wave * 16 + quad * 4;
#pragma unroll
        for (int ct = 0; ct < 4; ++ct) {
            int coll = lq + 16 * ct;
#pragma unroll
            for (int r = 0; r < 4; ++r) {
                int n = n0 + rowl + r;
                float v = acc[4][ct][r];
                size_t o = (size_t)(bidx * 4096 + n) * 32;
                if (coll < 32) {
                    v += bfb[coll];
                    unsigned short h = f2bf(v);
                    fKh[o + coll] = h;
                    fKl[o + coll] = f2bf(v - bf2f(h));
                } else {
                    v += bgb[coll - 32];
                    unsigned short h = f2bf(v);
                    gQh[o + (coll - 32)] = h;
                    gQl[o + (coll - 32)] = f2bf(v - bf2f(h));
                }
            }
        }
    }
}

// ---------------- kernel 2: flash attention, no staging --------------------
// Grid 256 = B(4) x 64 q-tiles of 64 rows; 4 waves, each wave owns 16 q-rows
// and ALL 256 channels. MFMA B-fragments (f, hT) loaded straight from global
// (16B/lane, L1-shared across the block's 4 waves). P transform through
// wave-private LDS. One light barrier per kt keeps waves lockstep for L1.
__global__ __launch_bounds__(256) void k_attn(
    const float* __restrict__ x,
    const float* __restrict__ gam_p,
    const unsigned short* __restrict__ fKh,
    const unsigned short* __restrict__ fKl,
    const unsigned short* __restrict__ gQh,
    const unsigned short* __restrict__ gQl,
    const unsigned short* __restrict__ hT,
    float* __restrict__ out) {
    __shared__ short Ps[4 * 16 * 72];     // per-wave P scratch [16][72]
    int tid = threadIdx.x;
    int wave = tid >> 6, lane = tid & 63, lq = lane & 15, quad = lane >> 4;
    int b = blockIdx.x >> 6, qt = blockIdx.x & 63;
    int qrow0 = qt * 64 + wave * 16;      // this wave's first q-row

    const unsigned short* fhB = fKh + (size_t)b * 4096 * 32;
    const unsigned short* flB = fKl + (size_t)b * 4096 * 32;
    const unsigned short* hB  = hT + (size_t)b * 256 * 4096;
    short* myP = &Ps[wave * 1152];

    f32x4 zero4 = {0.f, 0.f, 0.f, 0.f};
    f32x4 acc[16];
#pragma unroll
    for (int ct = 0; ct < 16; ++ct) acc[ct] = zero4;
    float m_i[4] = {-1e30f, -1e30f, -1e30f, -1e30f};
    float l_i[4] = {0.f, 0.f, 0.f, 0.f};

    size_t go = ((size_t)(b * 4096 + qrow0 + lq)) * 32 + quad * 8;
    short8 ghfrag = *(const short8*)&gQh[go];
    short8 glfrag = *(const short8*)&gQl[go];

    for (int kt = 0; kt < 64; ++kt) {
        int kbase = kt * 64;
        __syncthreads();   // keep waves lockstep (L1 fragment reuse)

        // ---- S = g.f^T (3-term hi/lo), B-frags direct from global ----
        f32x4 S[4];
#pragma unroll
        for (int t = 0; t < 4; ++t) {
            size_t fo = (size_t)(kbase + lq + 16 * t) * 32 + quad * 8;
            short8 fh = *(const short8*)&fhB[fo];
            short8 fl = *(const short8*)&flB[fo];
            S[t] = __builtin_amdgcn_mfma_f32_16x16x32_bf16(ghfrag, fh, zero4, 0, 0, 0);
            S[t] = __builtin_amdgcn_mfma_f32_16x16x32_bf16(glfrag, fh, S[t], 0, 0, 0);
            S[t] = __builtin_amdgcn_mfma_f32_16x16x32_bf16(ghfrag, fl, S[t], 0, 0, 0);
        }

        // ---- online softmax (state lives in the same lanes as acc rows) --
        float al[4];
#pragma unroll
        for (int r = 0; r < 4; ++r) {
            float mr = fmaxf(fmaxf(S[0][r], S[1][r]), fmaxf(S[2][r], S[3][r]));
            mr = fmaxf(mr, __shfl_xor(mr, 1));
            mr = fmaxf(mr, __shfl_xor(mr, 2));
            mr = fmaxf(mr, __shfl_xor(mr, 4));
            mr = fmaxf(mr, __shfl_xor(mr, 8));
            float mn = fmaxf(m_i[r], mr);
            al[r] = __expf(m_i[r] - mn);
            m_i[r] = mn;
        }
#pragma unroll
        for (int t = 0; t < 4; ++t)
#pragma unroll
            for (int r = 0; r < 4; ++r) S[t][r] = __expf(S[t][r] - m_i[r]);
#pragma unroll
        for (int r = 0; r < 4; ++r) {
            float s = S[0][r] + S[1][r] + S[2][r] + S[3][r];
            s += __shfl_xor(s, 1);
            s += __shfl_xor(s, 2);
            s += __shfl_xor(s, 4);
            s += __shfl_xor(s, 8);
            l_i[r] = l_i[r] * al[r] + s;
        }

        // ---- P: C-layout -> A-layout via wave-private LDS ----
#pragma unroll
        for (int t = 0; t < 4; ++t)
#pragma unroll
            for (int r = 0; r < 4; ++r)
                myP[(quad * 4 + r) * 72 + lq + 16 * t] = (short)f2bf(S[t][r]);
        short8 pa0 = *(const short8*)&myP[lq * 72 + quad * 8];
        short8 pa1 = *(const short8*)&myP[lq * 72 + 32 + quad * 8];

        // ---- rescale acc (skip when all alphas are 1) ----
        bool sk = (al[0] == 1.0f) && (al[1] == 1.0f) && (al[2] == 1.0f) && (al[3] == 1.0f);
        if (!__all((int)sk)) {
#pragma unroll
            for (int ct = 0; ct < 16; ++ct)
#pragma unroll
                for (int r = 0; r < 4; ++r) acc[ct][r] *= al[r];
        }

        // ---- PV: hT B-frags direct from global ----
#pragma unroll
        for (int ct = 0; ct < 16; ++ct) {
            const unsigned short* hp =
                hB + (size_t)(lq + 16 * ct) * 4096 + kbase + quad * 8;
            short8 hb0 = *(const short8*)hp;
            short8 hb1 = *(const short8*)(hp + 32);
            acc[ct] = __builtin_amdgcn_mfma_f32_16x16x32_bf16(pa0, hb0, acc[ct], 0, 0, 0);
            acc[ct] = __builtin_amdgcn_mfma_f32_16x16x32_bf16(pa1, hb1, acc[ct], 0, 0, 0);
        }
    }

    // ---- epilogue ----
    float gam = gam_p[0];
    float linv[4];
#pragma unroll
    for (int r = 0; r < 4; ++r) linv[r] = 1.0f / l_i[r];
#pragma unroll
    for (int ct = 0; ct < 16; ++ct) {
        int c = lq + 16 * ct;
#pragma unroll
        for (int r = 0; r < 4; ++r) {
            int n = qrow0 + quad * 4 + r;
            size_t idx = ((size_t)(b * 4096 + n)) * 256 + c;
            out[idx] = gam * (acc[ct][r] * linv[r]) + x[idx];
        }
    }
}

extern "C" void kernel_launch(void* const* d_in, const int* in_sizes, int n_in,
                              void* d_out, int out_size, void* d_ws, size_t ws_size,
                              hipStream_t stream) {
    const float* x   = (const float*)d_in[0];
    const float* Wf  = (const float*)d_in[1];
    const float* bfb = (const float*)d_in[2];
    const float* Wg  = (const float*)d_in[3];
    const float* bgb = (const float*)d_in[4];
    const float* Wh  = (const float*)d_in[5];
    const float* bhb = (const float*)d_in[6];
    const float* gam = (const float*)d_in[7];
    float* out = (float*)d_out;

    char* ws = (char*)d_ws;
    unsigned short* fKh = (unsigned short*)(ws);                          // 1 MB
    unsigned short* fKl = (unsigned short*)(ws + (1u << 20));             // 1 MB
    unsigned short* gQh = (unsigned short*)(ws + (2u << 20));             // 1 MB
    unsigned short* gQl = (unsigned short*)(ws + (3u << 20));             // 1 MB
    unsigned short* hT  = (unsigned short*)(ws + (4u << 20));             // 8 MB
    unsigned short* wTh = (unsigned short*)(ws + (12u << 20));            // 160 KB
    unsigned short* wTl = (unsigned short*)(ws + (12u << 20) + (256u << 10)); // 32 KB

    k_wtrans<<<dim3(320), dim3(256), 0, stream>>>(Wf, Wg, Wh, wTh, wTl);
    k_proj<<<dim3(256), dim3(256), 0, stream>>>(x, wTh, wTl, bfb, bgb, bhb,
                                                fKh, fKl, gQh, gQl, hT);
    k_attn<<<dim3(256), dim3(256), 0, stream>>>(x, gam, fKh, fKl, gQh, gQl, hT, out);
}

// Round 5
// 271.905 us; speedup vs baseline: 1.6314x; 1.6314x over previous
//
#include <hip/hip_runtime.h>
#include <stdint.h>

typedef short short8 __attribute__((ext_vector_type(8)));
typedef short short4_t __attribute__((ext_vector_type(4)));
typedef float f32x4 __attribute__((ext_vector_type(4)));

__device__ __forceinline__ float bf2f(unsigned short u) {
    union { unsigned int i; float f; } v; v.i = ((unsigned int)u) << 16; return v.f;
}
__device__ __forceinline__ unsigned short f2bf(float f) {
    union { float f; unsigned int i; } v; v.f = f;
    unsigned int u = v.i;
    unsigned int r = (u + 0x7fffu + ((u >> 16) & 1u)) >> 16;
    return (unsigned short)r;
}

// ---------------- kernel 0: weight transpose (f32 -> bf16 hi, + lo for f/g) -
__global__ void k_wtrans(const float* __restrict__ Wf,
                         const float* __restrict__ Wg,
                         const float* __restrict__ Wh,
                         unsigned short* __restrict__ wTh,
                         unsigned short* __restrict__ wTl) {
    int col = blockIdx.x;   // 0..319
    int k = threadIdx.x;    // 0..255
    float v;
    if (col < 32) v = Wf[k * 32 + col];
    else if (col < 64) v = Wg[k * 32 + (col - 32)];
    else v = Wh[k * 256 + (col - 64)];
    unsigned short h = f2bf(v);
    wTh[col * 256 + k] = h;
    if (col < 64) wTl[col * 256 + k] = f2bf(v - bf2f(h));
}

// ---------------- kernel 1a: f,g projection, 3-term split GEMM -------------
__global__ __launch_bounds__(256) void k_projfg(
    const float* __restrict__ x,
    const unsigned short* __restrict__ wTh,
    const unsigned short* __restrict__ wTl,
    const float* __restrict__ bfb,
    const float* __restrict__ bgb,
    unsigned short* __restrict__ fKh,
    unsigned short* __restrict__ fKl,
    unsigned short* __restrict__ gQh,
    unsigned short* __restrict__ gQl) {
    __shared__ short sm[4 * 64 * 72];   // XH, XL, WH, WL tiles [64][64->72]
    const int XH = 0, XL = 64 * 72, WH = 2 * 64 * 72, WL = 3 * 64 * 72;
    int tid = threadIdx.x;
    int wave = tid >> 6, lane = tid & 63, lq = lane & 15, quad = lane >> 4;
    int rt = blockIdx.x;
    const float* xbase = x + (size_t)rt * 64 * 256;

    f32x4 zero4 = {0.f, 0.f, 0.f, 0.f};
    f32x4 acc[4] = {zero4, zero4, zero4, zero4};

    for (int ph = 0; ph < 4; ++ph) {
        int k0 = ph * 64;
        __syncthreads();
#pragma unroll
        for (int u = 0; u < 2; ++u) {
            int q = u * 256 + tid;
            int row = q >> 3, kc = q & 7;
            const float* src = &xbase[row * 256 + k0 + kc * 8];
            f32x4 a0 = *(const f32x4*)src;
            f32x4 a1 = *(const f32x4*)(src + 4);
            short8 sh, sl;
#pragma unroll
            for (int j = 0; j < 4; ++j) {
                unsigned short h0 = f2bf(a0[j]);
                sh[j] = (short)h0; sl[j] = (short)f2bf(a0[j] - bf2f(h0));
                unsigned short h1 = f2bf(a1[j]);
                sh[4 + j] = (short)h1; sl[4 + j] = (short)f2bf(a1[j] - bf2f(h1));
            }
            *(short8*)&sm[XH + row * 72 + kc * 8] = sh;
            *(short8*)&sm[XL + row * 72 + kc * 8] = sl;
            *(short8*)&sm[WH + row * 72 + kc * 8] =
                *(const short8*)&wTh[row * 256 + k0 + kc * 8];
            *(short8*)&sm[WL + row * 72 + kc * 8] =
                *(const short8*)&wTl[row * 256 + k0 + kc * 8];
        }
        __syncthreads();
#pragma unroll
        for (int ks = 0; ks < 2; ++ks) {
            short8 ah = *(const short8*)&sm[XH + (wave * 16 + lq) * 72 + ks * 32 + quad * 8];
            short8 al = *(const short8*)&sm[XL + (wave * 16 + lq) * 72 + ks * 32 + quad * 8];
#pragma unroll
            for (int ct = 0; ct < 4; ++ct) {
                short8 bh = *(const short8*)&sm[WH + (lq + 16 * ct) * 72 + ks * 32 + quad * 8];
                short8 bl = *(const short8*)&sm[WL + (lq + 16 * ct) * 72 + ks * 32 + quad * 8];
                acc[ct] = __builtin_amdgcn_mfma_f32_16x16x32_bf16(ah, bh, acc[ct], 0, 0, 0);
                acc[ct] = __builtin_amdgcn_mfma_f32_16x16x32_bf16(al, bh, acc[ct], 0, 0, 0);
                acc[ct] = __builtin_amdgcn_mfma_f32_16x16x32_bf16(ah, bl, acc[ct], 0, 0, 0);
            }
        }
    }

    int rowl = wave * 16 + quad * 4;
#pragma unroll
    for (int ct = 0; ct < 4; ++ct) {
        int coll = lq + 16 * ct;
#pragma unroll
        for (int r = 0; r < 4; ++r) {
            int grow = rt * 64 + rowl + r;
            int bidx = grow >> 12, n = grow & 4095;
            float v = acc[ct][r];
            size_t o = (size_t)(bidx * 4096 + n) * 32;
            if (coll < 32) {
                v += bfb[coll];
                unsigned short h = f2bf(v);
                fKh[o + coll] = h;
                fKl[o + coll] = f2bf(v - bf2f(h));
            } else {
                v += bgb[coll - 32];
                unsigned short h = f2bf(v);
                gQh[o + (coll - 32)] = h;
                gQl[o + (coll - 32)] = f2bf(v - bf2f(h));
            }
        }
    }
}

// ---------------- kernel 1b: h projection GEMM -----------------------------
__global__ __launch_bounds__(256) void k_projh(
    const float* __restrict__ x,
    const unsigned short* __restrict__ wTh,
    const float* __restrict__ bhb,
    unsigned short* __restrict__ hT) {
    __shared__ short sm[2 * 64 * 136];
    const int XO = 0, WO = 64 * 136;
    int tid = threadIdx.x;
    int wave = tid >> 6, lane = tid & 63, lq = lane & 15, quad = lane >> 4;
    int rt = blockIdx.x;
    int cb = blockIdx.y;
    const float* xbase = x + (size_t)rt * 64 * 256;
    const unsigned short* wbase = wTh + (size_t)(64 + cb * 64) * 256;

    f32x4 zero4 = {0.f, 0.f, 0.f, 0.f};
    f32x4 acc[4] = {zero4, zero4, zero4, zero4};

    for (int ph = 0; ph < 2; ++ph) {
        int k0 = ph * 128;
        __syncthreads();
#pragma unroll
        for (int u = 0; u < 4; ++u) {
            int q = u * 256 + tid;
            int row = q >> 4, kc = q & 15;
            const float* src = &xbase[row * 256 + k0 + kc * 8];
            f32x4 a0 = *(const f32x4*)src;
            f32x4 a1 = *(const f32x4*)(src + 4);
            short8 s;
            s[0] = (short)f2bf(a0[0]); s[1] = (short)f2bf(a0[1]);
            s[2] = (short)f2bf(a0[2]); s[3] = (short)f2bf(a0[3]);
            s[4] = (short)f2bf(a1[0]); s[5] = (short)f2bf(a1[1]);
            s[6] = (short)f2bf(a1[2]); s[7] = (short)f2bf(a1[3]);
            *(short8*)&sm[XO + row * 136 + kc * 8] = s;
            *(short8*)&sm[WO + row * 136 + kc * 8] =
                *(const short8*)&wbase[row * 256 + k0 + kc * 8];
        }
        __syncthreads();
#pragma unroll
        for (int ks = 0; ks < 4; ++ks) {
            short8 a = *(const short8*)&sm[XO + (wave * 16 + lq) * 136 + ks * 32 + quad * 8];
#pragma unroll
            for (int ct = 0; ct < 4; ++ct) {
                short8 b = *(const short8*)&sm[WO + (lq + 16 * ct) * 136 + ks * 32 + quad * 8];
                acc[ct] = __builtin_amdgcn_mfma_f32_16x16x32_bf16(a, b, acc[ct], 0, 0, 0);
            }
        }
    }

    int rowl = wave * 16 + quad * 4;
    int grow0 = rt * 64;
    int bidx = grow0 >> 12, n0 = (grow0 & 4095) + rowl;
#pragma unroll
    for (int ct = 0; ct < 4; ++ct) {
        int c = cb * 64 + lq + 16 * ct;
        float bias = bhb[c];
        short4_t pk;
#pragma unroll
        for (int r = 0; r < 4; ++r) pk[r] = (short)f2bf(acc[ct][r] + bias);
        *(short4_t*)&hT[((size_t)(bidx * 256 + c)) * 4096 + n0] = pk;
    }
}

// ---------------- kernel 2: flash attention --------------------------------
// Grid 256 = B(4) x 64 q-tiles of 64 rows. 4 waves:
//   S-phase ROW-split: wave w computes S rows w*16..+16 (full softmax, local)
//   PV-phase COL-split: wave w owns channels w*64..+64 for ALL 64 rows.
// hT/f fragments straight from global (hT read exactly once per block);
// only P (bf16) + alpha/l go through LDS. 2 barriers per kt.
__global__ __launch_bounds__(256) void k_attn(
    const float* __restrict__ x,
    const float* __restrict__ gam_p,
    const unsigned short* __restrict__ fKh,
    const unsigned short* __restrict__ fKl,
    const unsigned short* __restrict__ gQh,
    const unsigned short* __restrict__ gQl,
    const unsigned short* __restrict__ hT,
    float* __restrict__ out) {
    __shared__ short Ps[4 * 16 * 72];   // per-S-wave P [16 rows][64 keys pad 72]
    __shared__ float af[64];
    __shared__ float lf[64];
    int tid = threadIdx.x;
    int wave = tid >> 6, lane = tid & 63, lq = lane & 15, quad = lane >> 4;
    int b = blockIdx.x >> 6, qt = blockIdx.x & 63;
    int qrow0 = qt * 64 + wave * 16;    // this wave's S rows

    const unsigned short* fhB = fKh + (size_t)b * 4096 * 32;
    const unsigned short* flB = fKl + (size_t)b * 4096 * 32;
    const unsigned short* hB  = hT + (size_t)b * 256 * 4096;
    short* myP = &Ps[wave * 1152];

    f32x4 zero4 = {0.f, 0.f, 0.f, 0.f};
    f32x4 acc[16];                      // [rb][ct]: rows rb*16+, cols wave*64+ct*16+
#pragma unroll
    for (int i = 0; i < 16; ++i) acc[i] = zero4;
    float m_i[4] = {-1e30f, -1e30f, -1e30f, -1e30f};
    float l_i[4] = {0.f, 0.f, 0.f, 0.f};

    size_t go = ((size_t)(b * 4096 + qrow0 + lq)) * 32 + quad * 8;
    short8 ghfrag = *(const short8*)&gQh[go];
    short8 glfrag = *(const short8*)&gQl[go];

    for (int kt = 0; kt < 64; ++kt) {
        int kbase = kt * 64;

        // ---- S = g.f^T (3-term hi/lo); f frags direct from global ----
        short8 fh[4], fl[4];
#pragma unroll
        for (int t = 0; t < 4; ++t) {
            size_t fo = (size_t)(kbase + t * 16 + lq) * 32 + quad * 8;
            fh[t] = *(const short8*)&fhB[fo];
            fl[t] = *(const short8*)&flB[fo];
        }
        f32x4 S[4];
#pragma unroll
        for (int t = 0; t < 4; ++t) {
            S[t] = __builtin_amdgcn_mfma_f32_16x16x32_bf16(ghfrag, fh[t], zero4, 0, 0, 0);
            S[t] = __builtin_amdgcn_mfma_f32_16x16x32_bf16(glfrag, fh[t], S[t], 0, 0, 0);
            S[t] = __builtin_amdgcn_mfma_f32_16x16x32_bf16(ghfrag, fl[t], S[t], 0, 0, 0);
        }

        // ---- wave-local online softmax for this wave's 16 rows ----
        float al[4];
#pragma unroll
        for (int r = 0; r < 4; ++r) {
            float mr = fmaxf(fmaxf(S[0][r], S[1][r]), fmaxf(S[2][r], S[3][r]));
            mr = fmaxf(mr, __shfl_xor(mr, 1));
            mr = fmaxf(mr, __shfl_xor(mr, 2));
            mr = fmaxf(mr, __shfl_xor(mr, 4));
            mr = fmaxf(mr, __shfl_xor(mr, 8));
            float mn = fmaxf(m_i[r], mr);
            al[r] = __expf(m_i[r] - mn);
            m_i[r] = mn;
        }
#pragma unroll
        for (int t = 0; t < 4; ++t)
#pragma unroll
            for (int r = 0; r < 4; ++r) S[t][r] = __expf(S[t][r] - m_i[r]);
#pragma unroll
        for (int r = 0; r < 4; ++r) {
            float s = S[0][r] + S[1][r] + S[2][r] + S[3][r];
            s += __shfl_xor(s, 1);
            s += __shfl_xor(s, 2);
            s += __shfl_xor(s, 4);
            s += __shfl_xor(s, 8);
            l_i[r] = l_i[r] * al[r] + s;
        }

        // ---- P (bf16) + alpha to LDS ----
#pragma unroll
        for (int t = 0; t < 4; ++t)
#pragma unroll
            for (int r = 0; r < 4; ++r)
                myP[(quad * 4 + r) * 72 + lq + 16 * t] = (short)f2bf(S[t][r]);
        if (lq == 0) {
#pragma unroll
            for (int r = 0; r < 4; ++r) af[wave * 16 + quad * 4 + r] = al[r];
        }

        // ---- hT frags for this wave's unique 64-channel slice ----
        short8 hb0[4], hb1[4];
#pragma unroll
        for (int ct = 0; ct < 4; ++ct) {
            int c = wave * 64 + ct * 16 + lq;
            const unsigned short* hp = hB + (size_t)c * 4096 + kbase + quad * 8;
            hb0[ct] = *(const short8*)hp;
            hb1[ct] = *(const short8*)(hp + 32);
        }

        __syncthreads();   // P + af visible

        // ---- alphas for all 4 row-blocks; skip rescale if all 1 ----
        f32x4 alv[4];
#pragma unroll
        for (int rb = 0; rb < 4; ++rb)
            alv[rb] = *(const f32x4*)&af[rb * 16 + quad * 4];
        bool sk = true;
#pragma unroll
        for (int rb = 0; rb < 4; ++rb)
#pragma unroll
            for (int r = 0; r < 4; ++r) sk = sk && (alv[rb][r] == 1.0f);
        if (!__all((int)sk)) {
#pragma unroll
            for (int rb = 0; rb < 4; ++rb)
#pragma unroll
                for (int ct = 0; ct < 4; ++ct)
#pragma unroll
                    for (int r = 0; r < 4; ++r) acc[rb * 4 + ct][r] *= alv[rb][r];
        }

        // ---- PV: all 64 rows x this wave's 64 channels ----
#pragma unroll
        for (int rb = 0; rb < 4; ++rb) {
            short8 pa0 = *(const short8*)&Ps[rb * 1152 + lq * 72 + quad * 8];
            short8 pa1 = *(const short8*)&Ps[rb * 1152 + lq * 72 + 32 + quad * 8];
#pragma unroll
            for (int ct = 0; ct < 4; ++ct) {
                acc[rb * 4 + ct] = __builtin_amdgcn_mfma_f32_16x16x32_bf16(pa0, hb0[ct], acc[rb * 4 + ct], 0, 0, 0);
                acc[rb * 4 + ct] = __builtin_amdgcn_mfma_f32_16x16x32_bf16(pa1, hb1[ct], acc[rb * 4 + ct], 0, 0, 0);
            }
        }

        __syncthreads();   // protect P/af before next kt overwrites
    }

    // ---- epilogue: share l across waves, write out ----
    if (lq == 0) {
#pragma unroll
        for (int r = 0; r < 4; ++r) lf[wave * 16 + quad * 4 + r] = l_i[r];
    }
    __syncthreads();

    float gam = gam_p[0];
#pragma unroll
    for (int rb = 0; rb < 4; ++rb) {
        f32x4 lv = *(const f32x4*)&lf[rb * 16 + quad * 4];
#pragma unroll
        for (int ct = 0; ct < 4; ++ct) {
            int c = wave * 64 + ct * 16 + lq;
#pragma unroll
            for (int r = 0; r < 4; ++r) {
                int n = qt * 64 + rb * 16 + quad * 4 + r;
                size_t idx = ((size_t)(b * 4096 + n)) * 256 + c;
                out[idx] = gam * (acc[rb * 4 + ct][r] / lv[r]) + x[idx];
            }
        }
    }
}

extern "C" void kernel_launch(void* const* d_in, const int* in_sizes, int n_in,
                              void* d_out, int out_size, void* d_ws, size_t ws_size,
                              hipStream_t stream) {
    const float* x   = (const float*)d_in[0];
    const float* Wf  = (const float*)d_in[1];
    const float* bfb = (const float*)d_in[2];
    const float* Wg  = (const float*)d_in[3];
    const float* bgb = (const float*)d_in[4];
    const float* Wh  = (const float*)d_in[5];
    const float* bhb = (const float*)d_in[6];
    const float* gam = (const float*)d_in[7];
    float* out = (float*)d_out;

    char* ws = (char*)d_ws;
    unsigned short* fKh = (unsigned short*)(ws);                          // 1 MB
    unsigned short* fKl = (unsigned short*)(ws + (1u << 20));             // 1 MB
    unsigned short* gQh = (unsigned short*)(ws + (2u << 20));             // 1 MB
    unsigned short* gQl = (unsigned short*)(ws + (3u << 20));             // 1 MB
    unsigned short* hT  = (unsigned short*)(ws + (4u << 20));             // 8 MB
    unsigned short* wTh = (unsigned short*)(ws + (12u << 20));            // 160 KB
    unsigned short* wTl = (unsigned short*)(ws + (12u << 20) + (256u << 10)); // 32 KB

    k_wtrans<<<dim3(320), dim3(256), 0, stream>>>(Wf, Wg, Wh, wTh, wTl);
    k_projfg<<<dim3(256), dim3(256), 0, stream>>>(x, wTh, wTl, bfb, bgb,
                                                  fKh, fKl, gQh, gQl);
    k_projh<<<dim3(256, 4), dim3(256), 0, stream>>>(x, wTh, bhb, hT);
    k_attn<<<dim3(256), dim3(256), 0, stream>>>(x, gam, fKh, fKl, gQh, gQl, hT, out);
}